// Round 4
// baseline (1044.017 us; speedup 1.0000x reference)
//
#include <hip/hip_runtime.h>
#include <math.h>

// GAT forward: 2x GATConv(single head) + fused MLP head.
// edge_index per harness: integer -> const int*.
// Softmax max-subtraction skipped (identical coefficients; |e| = O(1) with
// these weight scales so expf is safe in fp32).
// D=128 kernels use a column-pair layout: lane l owns columns {2l, 2l+1}
// (float2 loads/stores; row-major memory layout unchanged).

__device__ __forceinline__ float lrelu(float x) { return fmaxf(x, 0.2f * x); }

__device__ __forceinline__ float wave_reduce_sum(float v) {
    #pragma unroll
    for (int off = 32; off > 0; off >>= 1) v += __shfl_xor(v, off, 64);
    return v;
}

// ---------------- CSR build ----------------

__global__ void hist_kernel(const int* __restrict__ dst, int E, int* __restrict__ C) {
    int i = blockIdx.x * blockDim.x + threadIdx.x;
    if (i < E) atomicAdd(&C[dst[i]], 1);
}

// Phase A: per-block local exclusive scan (1024 elems/block) + block sums.
__global__ __launch_bounds__(1024)
void scan_local_kernel(const int* __restrict__ C, int* __restrict__ R,
                       int* __restrict__ bsum, int n) {
    __shared__ int wsum[16];
    const int tid = threadIdx.x, lane = tid & 63, wid = tid >> 6;
    const int i = blockIdx.x * 1024 + tid;
    int v = (i < n) ? C[i] : 0;
    int x = v;
    #pragma unroll
    for (int off = 1; off < 64; off <<= 1) {
        int t = __shfl_up(x, off, 64);
        if (lane >= off) x += t;
    }
    if (lane == 63) wsum[wid] = x;
    __syncthreads();
    if (wid == 0) {
        int w = (lane < 16) ? wsum[lane] : 0;
        #pragma unroll
        for (int off = 1; off < 16; off <<= 1) {
            int t = __shfl_up(w, off, 64);
            if (lane >= off) w += t;
        }
        if (lane < 16) wsum[lane] = w;
    }
    __syncthreads();
    int excl = ((wid == 0) ? 0 : wsum[wid - 1]) + x - v;
    if (i < n) R[i] = excl;   // local-exclusive for now
    if (tid == 0) bsum[blockIdx.x] = wsum[15];
}

// Phase B: exclusive scan of <=128 block sums, one wave.
__global__ void scan_bsum_kernel(int* __restrict__ bsum, int nb) {
    const int lane = threadIdx.x;
    int v0 = (lane < nb) ? bsum[lane] : 0;
    int v1 = (64 + lane < nb) ? bsum[64 + lane] : 0;
    int x0 = v0;
    #pragma unroll
    for (int off = 1; off < 64; off <<= 1) {
        int t = __shfl_up(x0, off, 64);
        if (lane >= off) x0 += t;
    }
    int tot0 = __shfl(x0, 63, 64);
    int x1 = v1;
    #pragma unroll
    for (int off = 1; off < 64; off <<= 1) {
        int t = __shfl_up(x1, off, 64);
        if (lane >= off) x1 += t;
    }
    if (lane < nb) bsum[lane] = x0 - v0;
    if (64 + lane < nb) bsum[64 + lane] = tot0 + x1 - v1;
}

// Phase C: add block offsets; also fill cursor array and R[n].
__global__ __launch_bounds__(1024)
void scan_apply_kernel(int* __restrict__ R, int* __restrict__ nxt,
                       const int* __restrict__ bsum, int n, int E) {
    const int i = blockIdx.x * 1024 + threadIdx.x;
    if (i < n) {
        int val = R[i] + bsum[blockIdx.x];
        R[i] = val;
        nxt[i] = val;
    }
    if (i == 0) R[n] = E;
}

__global__ void scatter_kernel(const int* __restrict__ src, const int* __restrict__ dst,
                               int E, int* __restrict__ nxt, int* __restrict__ csr) {
    int i = blockIdx.x * blockDim.x + threadIdx.x;
    if (i < E) {
        int p = atomicAdd(&nxt[dst[i]], 1);
        csr[p] = src[i];
    }
}

// ---------------- layer 1 GEMM: h1 = x @ W1 (128->64), alphas ----------------
// 4 rows per wave, shfl-broadcast x, W column load amortized 4x.

__global__ __launch_bounds__(256)
void gemm1_kernel(const float* __restrict__ x, const float* __restrict__ W1,
                  const float* __restrict__ a_s, const float* __restrict__ a_d,
                  float* __restrict__ h, float* __restrict__ as_o, float* __restrict__ ad_o,
                  int N) {
    const int lane = threadIdx.x & 63, wid = threadIdx.x >> 6;
    const int rowBase = (blockIdx.x * 4 + wid) * 4;
    if (rowBase >= N) return;
    const int nr = min(4, N - rowBase);
    float xl[4], xh[4];
    #pragma unroll
    for (int r = 0; r < 4; ++r) {
        if (r < nr) {
            const float* xp = x + (size_t)(rowBase + r) * 128;
            xl[r] = xp[lane];
            xh[r] = xp[64 + lane];
        } else { xl[r] = 0.f; xh[r] = 0.f; }
    }
    float acc[4] = {0.f, 0.f, 0.f, 0.f};
    #pragma unroll 8
    for (int k = 0; k < 64; ++k) {
        float wv = W1[k * 64 + lane];
        #pragma unroll
        for (int r = 0; r < 4; ++r) acc[r] = fmaf(__shfl(xl[r], k, 64), wv, acc[r]);
    }
    #pragma unroll 8
    for (int k = 0; k < 64; ++k) {
        float wv = W1[(64 + k) * 64 + lane];
        #pragma unroll
        for (int r = 0; r < 4; ++r) acc[r] = fmaf(__shfl(xh[r], k, 64), wv, acc[r]);
    }
    const float asv = a_s[lane], adv = a_d[lane];
    #pragma unroll
    for (int r = 0; r < 4; ++r) {
        if (r < nr) {
            h[(size_t)(rowBase + r) * 64 + lane] = acc[r];
            float ps = wave_reduce_sum(acc[r] * asv);
            float pd = wave_reduce_sum(acc[r] * adv);
            if (lane == 0) { as_o[rowBase + r] = ps; ad_o[rowBase + r] = pd; }
        }
    }
}

// ---------------- per-dst aggregation, D=64 ----------------
// One wave per node; first 64 edge weights cached in registers.

__global__ __launch_bounds__(256)
void agg1_kernel(const int* __restrict__ R, const int* __restrict__ csr,
                 const float* __restrict__ as1, const float* __restrict__ ad1,
                 const float* __restrict__ h1, const float* __restrict__ b1,
                 float* __restrict__ h1a, int N) {
    const int lane = threadIdx.x & 63;
    const int node = (int)((blockIdx.x * blockDim.x + threadIdx.x) >> 6);
    if (node >= N) return;
    const int start = R[node], end = R[node + 1];
    const float ad = ad1[node];
    int s0 = 0; float w0 = 0.f;
    const int e0 = start + lane;
    if (e0 < end) { s0 = csr[e0]; w0 = __expf(lrelu(as1[s0] + ad)); }
    float dsum = w0;
    for (int base = start + 64; base < end; base += 64) {  // rare (deg>64)
        int e = base + lane;
        if (e < end) dsum += __expf(lrelu(as1[csr[e]] + ad));
    }
    dsum = wave_reduce_sum(dsum);
    const float inv = 1.f / (dsum + 1e-16f);
    float acc = 0.f;
    const int cnt = min(64, end - start);
    for (int t = 0; t < cnt; ++t) {
        int st = __shfl(s0, t, 64);
        float wt = __shfl(w0, t, 64);
        acc += wt * h1[(size_t)st * 64 + lane];
    }
    for (int base = start + 64; base < end; base += 64) {  // rare tail
        int e = base + lane;
        int s = 0; float w = 0.f;
        if (e < end) { s = csr[e]; w = __expf(lrelu(as1[s] + ad)); }
        int c2 = min(64, end - base);
        for (int t = 0; t < c2; ++t)
            acc += __shfl(w, t, 64) * h1[(size_t)__shfl(s, t, 64) * 64 + lane];
    }
    acc = acc * inv + b1[lane];
    h1a[(size_t)node * 64 + lane] = fmaxf(acc, 0.f);
}

// ---------------- layer 2 GEMM: h2 = h1a @ W2 (64->128), alphas ----------------
// Column-pair layout: lane l -> columns {2l, 2l+1}.

__global__ __launch_bounds__(256)
void gemm2_kernel(const float* __restrict__ h1a, const float* __restrict__ W2,
                  const float* __restrict__ a_s, const float* __restrict__ a_d,
                  float* __restrict__ h2, float* __restrict__ as_o, float* __restrict__ ad_o,
                  int N) {
    const int lane = threadIdx.x & 63, wid = threadIdx.x >> 6;
    const int rowBase = (blockIdx.x * 4 + wid) * 4;
    if (rowBase >= N) return;
    const int nr = min(4, N - rowBase);
    float xv[4];
    #pragma unroll
    for (int r = 0; r < 4; ++r)
        xv[r] = (r < nr) ? h1a[(size_t)(rowBase + r) * 64 + lane] : 0.f;
    float a0[4] = {0.f,0.f,0.f,0.f}, a1[4] = {0.f,0.f,0.f,0.f};
    #pragma unroll 8
    for (int k = 0; k < 64; ++k) {
        const float2 w = *(const float2*)(W2 + k * 128 + 2 * lane);
        #pragma unroll
        for (int r = 0; r < 4; ++r) {
            float xk = __shfl(xv[r], k, 64);
            a0[r] = fmaf(xk, w.x, a0[r]);
            a1[r] = fmaf(xk, w.y, a1[r]);
        }
    }
    const float2 asv = *(const float2*)(a_s + 2 * lane);
    const float2 adv = *(const float2*)(a_d + 2 * lane);
    #pragma unroll
    for (int r = 0; r < 4; ++r) {
        if (r < nr) {
            float* hp = h2 + (size_t)(rowBase + r) * 128;
            *(float2*)(hp + 2 * lane) = make_float2(a0[r], a1[r]);
            float ps = wave_reduce_sum(a0[r] * asv.x + a1[r] * asv.y);
            float pd = wave_reduce_sum(a0[r] * adv.x + a1[r] * adv.y);
            if (lane == 0) { as_o[rowBase + r] = ps; ad_o[rowBase + r] = pd; }
        }
    }
}

// ---------------- per-dst aggregation, D=128 ----------------
// Column-pair layout: one 8B dwordx2 gather per lane per edge.

__global__ __launch_bounds__(256)
void agg2_kernel(const int* __restrict__ R, const int* __restrict__ csr,
                 const float* __restrict__ as2, const float* __restrict__ ad2,
                 const float* __restrict__ h2, const float* __restrict__ b2,
                 float* __restrict__ h2a, int N) {
    const int lane = threadIdx.x & 63;
    const int node = (int)((blockIdx.x * blockDim.x + threadIdx.x) >> 6);
    if (node >= N) return;
    const int start = R[node], end = R[node + 1];
    const float ad = ad2[node];
    int s0 = 0; float w0 = 0.f;
    const int e0 = start + lane;
    if (e0 < end) { s0 = csr[e0]; w0 = __expf(lrelu(as2[s0] + ad)); }
    float dsum = w0;
    for (int base = start + 64; base < end; base += 64) {   // rare (deg>64)
        int e = base + lane;
        if (e < end) dsum += __expf(lrelu(as2[csr[e]] + ad));
    }
    dsum = wave_reduce_sum(dsum);
    const float inv = 1.f / (dsum + 1e-16f);
    float a0 = 0.f, a1 = 0.f;
    const int cnt = min(64, end - start);
    for (int t = 0; t < cnt; ++t) {
        int st = __shfl(s0, t, 64);
        float wt = __shfl(w0, t, 64);
        const float2 hv = *(const float2*)(h2 + (size_t)st * 128 + 2 * lane);
        a0 = fmaf(wt, hv.x, a0);
        a1 = fmaf(wt, hv.y, a1);
    }
    for (int base = start + 64; base < end; base += 64) {   // rare tail
        int e = base + lane;
        int s = 0; float w = 0.f;
        if (e < end) { s = csr[e]; w = __expf(lrelu(as2[s] + ad)); }
        int c2 = min(64, end - base);
        for (int t = 0; t < c2; ++t) {
            int st = __shfl(s, t, 64);
            float wt = __shfl(w, t, 64);
            const float2 hv = *(const float2*)(h2 + (size_t)st * 128 + 2 * lane);
            a0 = fmaf(wt, hv.x, a0);
            a1 = fmaf(wt, hv.y, a1);
        }
    }
    const float2 bv = *(const float2*)(b2 + 2 * lane);
    *(float2*)(h2a + (size_t)node * 128 + 2 * lane) =
        make_float2(fmaxf(a0 * inv + bv.x, 0.f), fmaxf(a1 * inv + bv.y, 0.f));
}

// ---------------- fused MLP head (4 rows per wave, shfl-based) ----------------
// h2a read in column-pair layout; z-space (64) uses col=lane.

__global__ __launch_bounds__(256)
void mlp_kernel(const float* __restrict__ h2a,
                const float* __restrict__ l1w, const float* __restrict__ l1b,
                const float* __restrict__ l2w, const float* __restrict__ l2b,
                const float* __restrict__ l11w, const float* __restrict__ l11b,
                const float* __restrict__ lVw,
                float* __restrict__ out, float* __restrict__ partials, int N) {
    __shared__ float vsh[4];
    const int lane = threadIdx.x & 63, wid = threadIdx.x >> 6;
    const int rowBase = (blockIdx.x * 4 + wid) * 4;
    float pv = 0.f;
    if (rowBase < N) {
        const int nr = min(4, N - rowBase);
        float xl[4], xh[4];   // xl[r]=col 2*lane, xh[r]=col 2*lane+1
        #pragma unroll
        for (int r = 0; r < 4; ++r) {
            if (r < nr) {
                const float2 xp2 =
                    *(const float2*)(h2a + (size_t)(rowBase + r) * 128 + 2 * lane);
                xl[r] = xp2.x; xh[r] = xp2.y;
            } else { xl[r] = 0.f; xh[r] = 0.f; }
        }
        const float b1v = l1b[lane];
        float z1[4] = {b1v, b1v, b1v, b1v};
        #pragma unroll 4
        for (int t = 0; t < 64; ++t) {          // k = 2t (xl) and 2t+1 (xh)
            float w0 = l1w[(2 * t) * 64 + lane];
            float w1 = l1w[(2 * t + 1) * 64 + lane];
            #pragma unroll
            for (int r = 0; r < 4; ++r) {
                z1[r] = fmaf(__shfl(xl[r], t, 64), w0, z1[r]);
                z1[r] = fmaf(__shfl(xh[r], t, 64), w1, z1[r]);
            }
        }
        const float b2v = l2b[lane];
        float z2[4] = {b2v, b2v, b2v, b2v};
        #pragma unroll 8
        for (int k = 0; k < 64; ++k) {
            float wv = l2w[k * 64 + lane];
            #pragma unroll
            for (int r = 0; r < 4; ++r) z2[r] = fmaf(__shfl(z1[r], k, 64), wv, z2[r]);
        }
        // value partial: sum over active rows of <z2[r], lVw>
        float zsum = 0.f;
        #pragma unroll
        for (int r = 0; r < 4; ++r) if (r < nr) zsum += z2[r];
        pv = wave_reduce_sum(zsum * lVw[lane]);
        // out = tanh(z2 @ l11w + l11b)
        const float b3v = l11b[lane];
        float z3[4] = {b3v, b3v, b3v, b3v};
        #pragma unroll 8
        for (int k = 0; k < 64; ++k) {
            float wv = l11w[k * 64 + lane];
            #pragma unroll
            for (int r = 0; r < 4; ++r) z3[r] = fmaf(__shfl(z2[r], k, 64), wv, z3[r]);
        }
        #pragma unroll
        for (int r = 0; r < 4; ++r)
            if (r < nr) out[(size_t)(rowBase + r) * 64 + lane] = tanhf(z3[r]);
    }
    if (lane == 0) vsh[wid] = pv;
    __syncthreads();
    if (threadIdx.x == 0)
        partials[blockIdx.x] = vsh[0] + vsh[1] + vsh[2] + vsh[3];
}

__global__ void reduce_kernel(const float* __restrict__ partials, int n,
                              float* __restrict__ out_val,
                              const float* __restrict__ lVb, float invN) {
    __shared__ float sh[16];
    float s = 0.f;
    for (int i = threadIdx.x; i < n; i += 1024) s += partials[i];
    s = wave_reduce_sum(s);
    const int lane = threadIdx.x & 63, wid = threadIdx.x >> 6;
    if (lane == 0) sh[wid] = s;
    __syncthreads();
    if (wid == 0) {
        float t = (lane < 16) ? sh[lane] : 0.f;
        t = wave_reduce_sum(t);
        if (lane == 0) *out_val = t * invN + lVb[0];
    }
}

// ---------------- launch ----------------

extern "C" void kernel_launch(void* const* d_in, const int* in_sizes, int n_in,
                              void* d_out, int out_size, void* d_ws, size_t ws_size,
                              hipStream_t stream) {
    const float* x    = (const float*)d_in[0];
    const int*   ei   = (const int*)d_in[1];
    const float* W1   = (const float*)d_in[2];
    const float* a_s1 = (const float*)d_in[3];
    const float* a_d1 = (const float*)d_in[4];
    const float* b1   = (const float*)d_in[5];
    const float* W2   = (const float*)d_in[6];
    const float* a_s2 = (const float*)d_in[7];
    const float* a_d2 = (const float*)d_in[8];
    const float* b2   = (const float*)d_in[9];
    const float* l1w  = (const float*)d_in[10];
    const float* l1b  = (const float*)d_in[11];
    const float* l2w  = (const float*)d_in[12];
    const float* l2b  = (const float*)d_in[13];
    const float* l11w = (const float*)d_in[14];
    const float* l11b = (const float*)d_in[15];
    const float* lVw  = (const float*)d_in[16];
    const float* lVb  = (const float*)d_in[17];
    float* out = (float*)d_out;

    const int N = in_sizes[0] / 128;
    const int E = in_sizes[1] / 2;
    const int* src = ei;
    const int* dst = ei + E;

    char* base = (char*)d_ws;
    size_t off = 0;
    auto alloc = [&](size_t bytes) -> char* {
        char* p = base + off;
        off = (off + bytes + 255) & ~(size_t)255;
        return p;
    };
    float* h1   = (float*)alloc((size_t)N * 64 * 4);   // region A lower half
    float* h1a  = (float*)alloc((size_t)N * 64 * 4);   // region A upper half
    float* h2a  = h1;                                   // alias: h1|h1a dead by agg2
    float* h2   = (float*)alloc((size_t)N * 128 * 4);
    float* as1  = (float*)alloc((size_t)N * 4);
    float* ad1  = (float*)alloc((size_t)N * 4);
    float* as2  = (float*)alloc((size_t)N * 4);
    float* ad2  = (float*)alloc((size_t)N * 4);
    int*   C    = (int*)alloc((size_t)N * 4);
    int*   R    = (int*)alloc((size_t)(N + 1) * 4);
    int*   nxt  = (int*)alloc((size_t)N * 4);
    int*   csr  = (int*)alloc((size_t)E * 4);
    int*   bsum = (int*)alloc((size_t)128 * 4);
    const int nB16 = (N + 15) / 16;                    // gemm/mlp blocks (16 rows)
    const int nWB  = (N * 64 + 255) / 256;             // agg blocks (1 wave/node)
    float* partials = (float*)alloc((size_t)nB16 * 4);
    (void)ws_size; (void)n_in; (void)out_size;

    hipMemsetAsync(C, 0, (size_t)N * 4, stream);
    const int egrid = (E + 255) / 256;
    const int nbs = (N + 1023) / 1024;                 // 98 <= 128 (scan_bsum limit)
    hist_kernel<<<egrid, 256, 0, stream>>>(dst, E, C);
    scan_local_kernel<<<nbs, 1024, 0, stream>>>(C, R, bsum, N);
    scan_bsum_kernel<<<1, 64, 0, stream>>>(bsum, nbs);
    scan_apply_kernel<<<nbs, 1024, 0, stream>>>(R, nxt, bsum, N, E);
    scatter_kernel<<<egrid, 256, 0, stream>>>(src, dst, E, nxt, csr);
    gemm1_kernel<<<nB16, 256, 0, stream>>>(x, W1, a_s1, a_d1, h1, as1, ad1, N);
    agg1_kernel<<<nWB, 256, 0, stream>>>(R, csr, as1, ad1, h1, b1, h1a, N);
    gemm2_kernel<<<nB16, 256, 0, stream>>>(h1a, W2, a_s2, a_d2, h2, as2, ad2, N);
    agg2_kernel<<<nWB, 256, 0, stream>>>(R, csr, as2, ad2, h2, b2, h2a, N);
    mlp_kernel<<<nB16, 256, 0, stream>>>(h2a, l1w, l1b, l2w, l2b, l11w, l11b, lVw,
                                         out, partials, N);
    reduce_kernel<<<1, 1024, 0, stream>>>(partials, nB16, out + (size_t)N * 64, lVb,
                                          1.0f / (float)N);
}

// Round 5
// 741.901 us; speedup vs baseline: 1.4072x; 1.4072x over previous
//
#include <hip/hip_runtime.h>
#include <math.h>

// GAT forward: 2x GATConv(single head) + fused MLP head.
// Dense kernels (gemm1/gemm2/mlp): one THREAD per node row, 64 accumulators
// in registers, weight addresses are wave-uniform (scalar/L1-broadcast loads),
// no shfl in hot loops. MLP inter-layer z[k] dynamic access goes through a
// padded per-thread LDS row (stride 65 -> conflict-free; no barriers needed).
// Softmax max-subtraction skipped (identical coefficients; |e| = O(1)).
// h2 consumed by agg2 in column-pair float2 layout (row-major unchanged).

__device__ __forceinline__ float lrelu(float x) { return fmaxf(x, 0.2f * x); }

__device__ __forceinline__ float wave_reduce_sum(float v) {
    #pragma unroll
    for (int off = 32; off > 0; off >>= 1) v += __shfl_xor(v, off, 64);
    return v;
}

__device__ __forceinline__ float fast_tanh(float x) {
    // tanh(x) = 1 - 2/(e^{2x}+1); rcp approx is ~1 ulp, fine at 1e-3 tolerance.
    float e = __expf(2.f * x);
    return 1.f - 2.f * __builtin_amdgcn_rcpf(e + 1.f);
}

// ---------------- CSR build ----------------

__global__ void hist_kernel(const int* __restrict__ dst, int E, int* __restrict__ C) {
    int i = blockIdx.x * blockDim.x + threadIdx.x;
    if (i < E) atomicAdd(&C[dst[i]], 1);
}

// Phase A: per-block local exclusive scan (1024 elems/block) + block sums.
__global__ __launch_bounds__(1024)
void scan_local_kernel(const int* __restrict__ C, int* __restrict__ R,
                       int* __restrict__ bsum, int n) {
    __shared__ int wsum[16];
    const int tid = threadIdx.x, lane = tid & 63, wid = tid >> 6;
    const int i = blockIdx.x * 1024 + tid;
    int v = (i < n) ? C[i] : 0;
    int x = v;
    #pragma unroll
    for (int off = 1; off < 64; off <<= 1) {
        int t = __shfl_up(x, off, 64);
        if (lane >= off) x += t;
    }
    if (lane == 63) wsum[wid] = x;
    __syncthreads();
    if (wid == 0) {
        int w = (lane < 16) ? wsum[lane] : 0;
        #pragma unroll
        for (int off = 1; off < 16; off <<= 1) {
            int t = __shfl_up(w, off, 64);
            if (lane >= off) w += t;
        }
        if (lane < 16) wsum[lane] = w;
    }
    __syncthreads();
    int excl = ((wid == 0) ? 0 : wsum[wid - 1]) + x - v;
    if (i < n) R[i] = excl;   // local-exclusive for now
    if (tid == 0) bsum[blockIdx.x] = wsum[15];
}

// Phase B: exclusive scan of <=128 block sums, one wave.
__global__ void scan_bsum_kernel(int* __restrict__ bsum, int nb) {
    const int lane = threadIdx.x;
    int v0 = (lane < nb) ? bsum[lane] : 0;
    int v1 = (64 + lane < nb) ? bsum[64 + lane] : 0;
    int x0 = v0;
    #pragma unroll
    for (int off = 1; off < 64; off <<= 1) {
        int t = __shfl_up(x0, off, 64);
        if (lane >= off) x0 += t;
    }
    int tot0 = __shfl(x0, 63, 64);
    int x1 = v1;
    #pragma unroll
    for (int off = 1; off < 64; off <<= 1) {
        int t = __shfl_up(x1, off, 64);
        if (lane >= off) x1 += t;
    }
    if (lane < nb) bsum[lane] = x0 - v0;
    if (64 + lane < nb) bsum[64 + lane] = tot0 + x1 - v1;
}

// Phase C: add block offsets; also fill cursor array and R[n].
__global__ __launch_bounds__(1024)
void scan_apply_kernel(int* __restrict__ R, int* __restrict__ nxt,
                       const int* __restrict__ bsum, int n, int E) {
    const int i = blockIdx.x * 1024 + threadIdx.x;
    if (i < n) {
        int val = R[i] + bsum[blockIdx.x];
        R[i] = val;
        nxt[i] = val;
    }
    if (i == 0) R[n] = E;
}

__global__ void scatter_kernel(const int* __restrict__ src, const int* __restrict__ dst,
                               int E, int* __restrict__ nxt, int* __restrict__ csr) {
    int i = blockIdx.x * blockDim.x + threadIdx.x;
    if (i < E) {
        int p = atomicAdd(&nxt[dst[i]], 1);
        csr[p] = src[i];
    }
}

// ---------------- layer 1 GEMM: h1 = x @ W1 (128->64), alphas ----------------
// Thread-per-row. Tail threads clamp to row N-1 (duplicate identical work).

__global__ __launch_bounds__(256)
void gemm1_kernel(const float* __restrict__ x, const float* __restrict__ W1,
                  const float* __restrict__ a_s, const float* __restrict__ a_d,
                  float* __restrict__ h, float* __restrict__ as_o, float* __restrict__ ad_o,
                  int N) {
    const int g = blockIdx.x * blockDim.x + threadIdx.x;
    const int row = min(g, N - 1);
    const float* __restrict__ xp = x + (size_t)row * 128;
    float z[64];
    #pragma unroll
    for (int j = 0; j < 64; ++j) z[j] = 0.f;
    #pragma unroll 2
    for (int c = 0; c < 32; ++c) {
        const float4 xv = *(const float4*)(xp + c * 4);
        const float* __restrict__ Wp = W1 + c * 4 * 64;   // wave-uniform address
        #pragma unroll
        for (int j = 0; j < 64; ++j) z[j] = fmaf(xv.x, Wp[j], z[j]);
        #pragma unroll
        for (int j = 0; j < 64; ++j) z[j] = fmaf(xv.y, Wp[64 + j], z[j]);
        #pragma unroll
        for (int j = 0; j < 64; ++j) z[j] = fmaf(xv.z, Wp[128 + j], z[j]);
        #pragma unroll
        for (int j = 0; j < 64; ++j) z[j] = fmaf(xv.w, Wp[192 + j], z[j]);
    }
    float ps = 0.f, pd = 0.f;
    #pragma unroll
    for (int j = 0; j < 64; ++j) {
        ps = fmaf(z[j], a_s[j], ps);
        pd = fmaf(z[j], a_d[j], pd);
    }
    float* __restrict__ hp = h + (size_t)row * 64;
    #pragma unroll
    for (int j = 0; j < 16; ++j)
        *(float4*)(hp + j * 4) = make_float4(z[4*j], z[4*j+1], z[4*j+2], z[4*j+3]);
    as_o[row] = ps;
    ad_o[row] = pd;
}

// ---------------- per-dst aggregation, D=64 ----------------
// One wave per node; first 64 edge weights cached in registers.

__global__ __launch_bounds__(256)
void agg1_kernel(const int* __restrict__ R, const int* __restrict__ csr,
                 const float* __restrict__ as1, const float* __restrict__ ad1,
                 const float* __restrict__ h1, const float* __restrict__ b1,
                 float* __restrict__ h1a, int N) {
    const int lane = threadIdx.x & 63;
    const int node = (int)((blockIdx.x * blockDim.x + threadIdx.x) >> 6);
    if (node >= N) return;
    const int start = R[node], end = R[node + 1];
    const float ad = ad1[node];
    int s0 = 0; float w0 = 0.f;
    const int e0 = start + lane;
    if (e0 < end) { s0 = csr[e0]; w0 = __expf(lrelu(as1[s0] + ad)); }
    float dsum = w0;
    for (int base = start + 64; base < end; base += 64) {  // rare (deg>64)
        int e = base + lane;
        if (e < end) dsum += __expf(lrelu(as1[csr[e]] + ad));
    }
    dsum = wave_reduce_sum(dsum);
    const float inv = 1.f / (dsum + 1e-16f);
    float acc = 0.f;
    const int cnt = min(64, end - start);
    for (int t = 0; t < cnt; ++t) {
        int st = __shfl(s0, t, 64);
        float wt = __shfl(w0, t, 64);
        acc += wt * h1[(size_t)st * 64 + lane];
    }
    for (int base = start + 64; base < end; base += 64) {  // rare tail
        int e = base + lane;
        int s = 0; float w = 0.f;
        if (e < end) { s = csr[e]; w = __expf(lrelu(as1[s] + ad)); }
        int c2 = min(64, end - base);
        for (int t = 0; t < c2; ++t)
            acc += __shfl(w, t, 64) * h1[(size_t)__shfl(s, t, 64) * 64 + lane];
    }
    acc = acc * inv + b1[lane];
    h1a[(size_t)node * 64 + lane] = fmaxf(acc, 0.f);
}

// ---------------- layer 2 GEMM: h2 = h1a @ W2 (64->128), alphas ----------------
// Thread-per-row, two 64-column halves (z regs bounded at 64).

__global__ __launch_bounds__(256)
void gemm2_kernel(const float* __restrict__ h1a, const float* __restrict__ W2,
                  const float* __restrict__ a_s, const float* __restrict__ a_d,
                  float* __restrict__ h2, float* __restrict__ as_o, float* __restrict__ ad_o,
                  int N) {
    const int g = blockIdx.x * blockDim.x + threadIdx.x;
    const int row = min(g, N - 1);
    const float* __restrict__ xp = h1a + (size_t)row * 64;
    float* __restrict__ hp = h2 + (size_t)row * 128;
    float ps = 0.f, pd = 0.f;
    for (int half = 0; half < 2; ++half) {
        float z[64];
        #pragma unroll
        for (int j = 0; j < 64; ++j) z[j] = 0.f;
        #pragma unroll 2
        for (int c = 0; c < 16; ++c) {
            const float4 xv = *(const float4*)(xp + c * 4);   // L1-hit on 2nd half
            const float* __restrict__ Wp = W2 + (c * 4) * 128 + half * 64;
            #pragma unroll
            for (int j = 0; j < 64; ++j) z[j] = fmaf(xv.x, Wp[j], z[j]);
            #pragma unroll
            for (int j = 0; j < 64; ++j) z[j] = fmaf(xv.y, Wp[128 + j], z[j]);
            #pragma unroll
            for (int j = 0; j < 64; ++j) z[j] = fmaf(xv.z, Wp[256 + j], z[j]);
            #pragma unroll
            for (int j = 0; j < 64; ++j) z[j] = fmaf(xv.w, Wp[384 + j], z[j]);
        }
        const float* __restrict__ asp = a_s + half * 64;
        const float* __restrict__ adp = a_d + half * 64;
        #pragma unroll
        for (int j = 0; j < 64; ++j) {
            ps = fmaf(z[j], asp[j], ps);
            pd = fmaf(z[j], adp[j], pd);
        }
        float* __restrict__ op = hp + half * 64;
        #pragma unroll
        for (int j = 0; j < 16; ++j)
            *(float4*)(op + j * 4) = make_float4(z[4*j], z[4*j+1], z[4*j+2], z[4*j+3]);
    }
    as_o[row] = ps;
    ad_o[row] = pd;
}

// ---------------- per-dst aggregation, D=128 ----------------
// Column-pair layout: one 8B dwordx2 gather per lane per edge.

__global__ __launch_bounds__(256)
void agg2_kernel(const int* __restrict__ R, const int* __restrict__ csr,
                 const float* __restrict__ as2, const float* __restrict__ ad2,
                 const float* __restrict__ h2, const float* __restrict__ b2,
                 float* __restrict__ h2a, int N) {
    const int lane = threadIdx.x & 63;
    const int node = (int)((blockIdx.x * blockDim.x + threadIdx.x) >> 6);
    if (node >= N) return;
    const int start = R[node], end = R[node + 1];
    const float ad = ad2[node];
    int s0 = 0; float w0 = 0.f;
    const int e0 = start + lane;
    if (e0 < end) { s0 = csr[e0]; w0 = __expf(lrelu(as2[s0] + ad)); }
    float dsum = w0;
    for (int base = start + 64; base < end; base += 64) {   // rare (deg>64)
        int e = base + lane;
        if (e < end) dsum += __expf(lrelu(as2[csr[e]] + ad));
    }
    dsum = wave_reduce_sum(dsum);
    const float inv = 1.f / (dsum + 1e-16f);
    float a0 = 0.f, a1 = 0.f;
    const int cnt = min(64, end - start);
    for (int t = 0; t < cnt; ++t) {
        int st = __shfl(s0, t, 64);
        float wt = __shfl(w0, t, 64);
        const float2 hv = *(const float2*)(h2 + (size_t)st * 128 + 2 * lane);
        a0 = fmaf(wt, hv.x, a0);
        a1 = fmaf(wt, hv.y, a1);
    }
    for (int base = start + 64; base < end; base += 64) {   // rare tail
        int e = base + lane;
        int s = 0; float w = 0.f;
        if (e < end) { s = csr[e]; w = __expf(lrelu(as2[s] + ad)); }
        int c2 = min(64, end - base);
        for (int t = 0; t < c2; ++t) {
            int st = __shfl(s, t, 64);
            float wt = __shfl(w, t, 64);
            const float2 hv = *(const float2*)(h2 + (size_t)st * 128 + 2 * lane);
            a0 = fmaf(wt, hv.x, a0);
            a1 = fmaf(wt, hv.y, a1);
        }
    }
    const float2 bv = *(const float2*)(b2 + 2 * lane);
    *(float2*)(h2a + (size_t)node * 128 + 2 * lane) =
        make_float2(fmaxf(a0 * inv + bv.x, 0.f), fmaxf(a1 * inv + bv.y, 0.f));
}

// ---------------- fused MLP head: thread-per-row ----------------
// Block = 192 threads; per-thread 65-float padded LDS row for z (49.9KB static).
// No barriers needed: each thread reads/writes only its own LDS row.

__global__ __launch_bounds__(192)
void mlp_kernel(const float* __restrict__ h2a,
                const float* __restrict__ l1w, const float* __restrict__ l1b,
                const float* __restrict__ l2w, const float* __restrict__ l2b,
                const float* __restrict__ l11w, const float* __restrict__ l11b,
                const float* __restrict__ lVw,
                float* __restrict__ out, float* __restrict__ partials, int N) {
    __shared__ float zs[192 * 65];
    __shared__ float vsh[3];
    const int tid = threadIdx.x;
    const int g = blockIdx.x * 192 + tid;
    const int row = min(g, N - 1);
    float* __restrict__ zrow = &zs[tid * 65];

    // layer 1: z1 = h2a_row @ l1w + l1b   (128 -> 64)
    const float* __restrict__ xp = h2a + (size_t)row * 128;
    float z1[64];
    #pragma unroll
    for (int j = 0; j < 64; ++j) z1[j] = l1b[j];
    #pragma unroll 2
    for (int c = 0; c < 32; ++c) {
        const float4 xv = *(const float4*)(xp + c * 4);
        const float* __restrict__ Wp = l1w + c * 4 * 64;
        #pragma unroll
        for (int j = 0; j < 64; ++j) z1[j] = fmaf(xv.x, Wp[j], z1[j]);
        #pragma unroll
        for (int j = 0; j < 64; ++j) z1[j] = fmaf(xv.y, Wp[64 + j], z1[j]);
        #pragma unroll
        for (int j = 0; j < 64; ++j) z1[j] = fmaf(xv.z, Wp[128 + j], z1[j]);
        #pragma unroll
        for (int j = 0; j < 64; ++j) z1[j] = fmaf(xv.w, Wp[192 + j], z1[j]);
    }
    #pragma unroll
    for (int j = 0; j < 64; ++j) zrow[j] = z1[j];

    // layer 2: z2 = z1 @ l2w + l2b   (64 -> 64)
    float z2[64];
    #pragma unroll
    for (int j = 0; j < 64; ++j) z2[j] = l2b[j];
    #pragma unroll 4
    for (int k = 0; k < 64; ++k) {
        const float zk = zrow[k];
        const float* __restrict__ Wp = l2w + k * 64;
        #pragma unroll
        for (int j = 0; j < 64; ++j) z2[j] = fmaf(zk, Wp[j], z2[j]);
    }

    // value partial: <z2, lVw>, zeroed for duplicate tail threads
    float v = 0.f;
    #pragma unroll
    for (int j = 0; j < 64; ++j) v = fmaf(z2[j], lVw[j], v);
    if (g >= N) v = 0.f;

    #pragma unroll
    for (int j = 0; j < 64; ++j) zrow[j] = z2[j];

    // layer 3: out = tanh(z2 @ l11w + l11b)   (64 -> 64)
    float z3[64];
    #pragma unroll
    for (int j = 0; j < 64; ++j) z3[j] = l11b[j];
    #pragma unroll 4
    for (int k = 0; k < 64; ++k) {
        const float zk = zrow[k];
        const float* __restrict__ Wp = l11w + k * 64;
        #pragma unroll
        for (int j = 0; j < 64; ++j) z3[j] = fmaf(zk, Wp[j], z3[j]);
    }
    float* __restrict__ op = out + (size_t)row * 64;
    #pragma unroll
    for (int j = 0; j < 16; ++j)
        *(float4*)(op + j * 4) = make_float4(fast_tanh(z3[4*j]),   fast_tanh(z3[4*j+1]),
                                             fast_tanh(z3[4*j+2]), fast_tanh(z3[4*j+3]));

    // block partial for the value mean
    v = wave_reduce_sum(v);
    const int lane = tid & 63, wid = tid >> 6;
    if (lane == 0) vsh[wid] = v;
    __syncthreads();
    if (tid == 0) partials[blockIdx.x] = vsh[0] + vsh[1] + vsh[2];
}

__global__ void reduce_kernel(const float* __restrict__ partials, int n,
                              float* __restrict__ out_val,
                              const float* __restrict__ lVb, float invN) {
    __shared__ float sh[16];
    float s = 0.f;
    for (int i = threadIdx.x; i < n; i += 1024) s += partials[i];
    s = wave_reduce_sum(s);
    const int lane = threadIdx.x & 63, wid = threadIdx.x >> 6;
    if (lane == 0) sh[wid] = s;
    __syncthreads();
    if (wid == 0) {
        float t = (lane < 16) ? sh[lane] : 0.f;
        t = wave_reduce_sum(t);
        if (lane == 0) *out_val = t * invN + lVb[0];
    }
}

// ---------------- launch ----------------

extern "C" void kernel_launch(void* const* d_in, const int* in_sizes, int n_in,
                              void* d_out, int out_size, void* d_ws, size_t ws_size,
                              hipStream_t stream) {
    const float* x    = (const float*)d_in[0];
    const int*   ei   = (const int*)d_in[1];
    const float* W1   = (const float*)d_in[2];
    const float* a_s1 = (const float*)d_in[3];
    const float* a_d1 = (const float*)d_in[4];
    const float* b1   = (const float*)d_in[5];
    const float* W2   = (const float*)d_in[6];
    const float* a_s2 = (const float*)d_in[7];
    const float* a_d2 = (const float*)d_in[8];
    const float* b2   = (const float*)d_in[9];
    const float* l1w  = (const float*)d_in[10];
    const float* l1b  = (const float*)d_in[11];
    const float* l2w  = (const float*)d_in[12];
    const float* l2b  = (const float*)d_in[13];
    const float* l11w = (const float*)d_in[14];
    const float* l11b = (const float*)d_in[15];
    const float* lVw  = (const float*)d_in[16];
    const float* lVb  = (const float*)d_in[17];
    float* out = (float*)d_out;

    const int N = in_sizes[0] / 128;
    const int E = in_sizes[1] / 2;
    const int* src = ei;
    const int* dst = ei + E;

    char* base = (char*)d_ws;
    size_t off = 0;
    auto alloc = [&](size_t bytes) -> char* {
        char* p = base + off;
        off = (off + bytes + 255) & ~(size_t)255;
        return p;
    };
    float* h1   = (float*)alloc((size_t)N * 64 * 4);   // region A lower half
    float* h1a  = (float*)alloc((size_t)N * 64 * 4);   // region A upper half
    float* h2a  = h1;                                   // alias: h1|h1a dead by agg2
    float* h2   = (float*)alloc((size_t)N * 128 * 4);
    float* as1  = (float*)alloc((size_t)N * 4);
    float* ad1  = (float*)alloc((size_t)N * 4);
    float* as2  = (float*)alloc((size_t)N * 4);
    float* ad2  = (float*)alloc((size_t)N * 4);
    int*   C    = (int*)alloc((size_t)N * 4);
    int*   R    = (int*)alloc((size_t)(N + 1) * 4);
    int*   nxt  = (int*)alloc((size_t)N * 4);
    int*   csr  = (int*)alloc((size_t)E * 4);
    int*   bsum = (int*)alloc((size_t)128 * 4);
    const int nB256 = (N + 255) / 256;                 // gemm blocks (256 rows)
    const int nBmlp = (N + 191) / 192;                 // mlp blocks (192 rows)
    const int nWB   = (N * 64 + 255) / 256;            // agg blocks (1 wave/node)
    float* partials = (float*)alloc((size_t)nBmlp * 4);
    (void)ws_size; (void)n_in; (void)out_size;

    hipMemsetAsync(C, 0, (size_t)N * 4, stream);
    const int egrid = (E + 255) / 256;
    const int nbs = (N + 1023) / 1024;                 // 98 <= 128 (scan_bsum limit)
    hist_kernel<<<egrid, 256, 0, stream>>>(dst, E, C);
    scan_local_kernel<<<nbs, 1024, 0, stream>>>(C, R, bsum, N);
    scan_bsum_kernel<<<1, 64, 0, stream>>>(bsum, nbs);
    scan_apply_kernel<<<nbs, 1024, 0, stream>>>(R, nxt, bsum, N, E);
    scatter_kernel<<<egrid, 256, 0, stream>>>(src, dst, E, nxt, csr);
    gemm1_kernel<<<nB256, 256, 0, stream>>>(x, W1, a_s1, a_d1, h1, as1, ad1, N);
    agg1_kernel<<<nWB, 256, 0, stream>>>(R, csr, as1, ad1, h1, b1, h1a, N);
    gemm2_kernel<<<nB256, 256, 0, stream>>>(h1a, W2, a_s2, a_d2, h2, as2, ad2, N);
    agg2_kernel<<<nWB, 256, 0, stream>>>(R, csr, as2, ad2, h2, b2, h2a, N);
    mlp_kernel<<<nBmlp, 192, 0, stream>>>(h2a, l1w, l1b, l2w, l2b, l11w, l11b, lVw,
                                          out, partials, N);
    reduce_kernel<<<1, 1024, 0, stream>>>(partials, nBmlp, out + (size_t)N * 64, lVb,
                                          1.0f / (float)N);
}

// Round 12
// 718.686 us; speedup vs baseline: 1.4527x; 1.0323x over previous
//
#include <hip/hip_runtime.h>
#include <math.h>

// GAT forward: 2x GATConv(single head) + fused MLP head.
// Dense kernels: thread-per-row, wave-uniform weight addresses; no shfl in
// hot loops. MLP uses a per-thread padded LDS row (stride 65, conflict-free,
// no barriers) for the inter-layer z vector -- bounded codegen (the fully
// register-resident variant appeared to kill the container at compile).
// Agg kernels: wave-per-node, edge weights cached in registers, gather loop
// unrolled 8-wide so 8 independent VMEM gathers are in flight per wave.
// Softmax max-subtraction skipped (identical coefficients; |e| = O(1)).
// h2 consumed by agg2 in column-pair float2 layout (row-major unchanged).

__device__ __forceinline__ float lrelu(float x) { return fmaxf(x, 0.2f * x); }

__device__ __forceinline__ float wave_reduce_sum(float v) {
    #pragma unroll
    for (int off = 32; off > 0; off >>= 1) v += __shfl_xor(v, off, 64);
    return v;
}

__device__ __forceinline__ float fast_tanh(float x) {
    float e = __expf(2.f * x);
    return 1.f - 2.f * __builtin_amdgcn_rcpf(e + 1.f);
}

// ---------------- CSR build ----------------

__global__ void hist_kernel(const int* __restrict__ dst, int E, int* __restrict__ C) {
    int i = blockIdx.x * blockDim.x + threadIdx.x;
    if (i < E) atomicAdd(&C[dst[i]], 1);
}

__global__ __launch_bounds__(1024)
void scan_local_kernel(const int* __restrict__ C, int* __restrict__ R,
                       int* __restrict__ bsum, int n) {
    __shared__ int wsum[16];
    const int tid = threadIdx.x, lane = tid & 63, wid = tid >> 6;
    const int i = blockIdx.x * 1024 + tid;
    int v = (i < n) ? C[i] : 0;
    int x = v;
    #pragma unroll
    for (int off = 1; off < 64; off <<= 1) {
        int t = __shfl_up(x, off, 64);
        if (lane >= off) x += t;
    }
    if (lane == 63) wsum[wid] = x;
    __syncthreads();
    if (wid == 0) {
        int w = (lane < 16) ? wsum[lane] : 0;
        #pragma unroll
        for (int off = 1; off < 16; off <<= 1) {
            int t = __shfl_up(w, off, 64);
            if (lane >= off) w += t;
        }
        if (lane < 16) wsum[lane] = w;
    }
    __syncthreads();
    int excl = ((wid == 0) ? 0 : wsum[wid - 1]) + x - v;
    if (i < n) R[i] = excl;
    if (tid == 0) bsum[blockIdx.x] = wsum[15];
}

__global__ void scan_bsum_kernel(int* __restrict__ bsum, int nb) {
    const int lane = threadIdx.x;
    int v0 = (lane < nb) ? bsum[lane] : 0;
    int v1 = (64 + lane < nb) ? bsum[64 + lane] : 0;
    int x0 = v0;
    #pragma unroll
    for (int off = 1; off < 64; off <<= 1) {
        int t = __shfl_up(x0, off, 64);
        if (lane >= off) x0 += t;
    }
    int tot0 = __shfl(x0, 63, 64);
    int x1 = v1;
    #pragma unroll
    for (int off = 1; off < 64; off <<= 1) {
        int t = __shfl_up(x1, off, 64);
        if (lane >= off) x1 += t;
    }
    if (lane < nb) bsum[lane] = x0 - v0;
    if (64 + lane < nb) bsum[64 + lane] = tot0 + x1 - v1;
}

__global__ __launch_bounds__(1024)
void scan_apply_kernel(int* __restrict__ R, int* __restrict__ nxt,
                       const int* __restrict__ bsum, int n, int E) {
    const int i = blockIdx.x * 1024 + threadIdx.x;
    if (i < n) {
        int val = R[i] + bsum[blockIdx.x];
        R[i] = val;
        nxt[i] = val;
    }
    if (i == 0) R[n] = E;
}

__global__ void scatter_kernel(const int* __restrict__ src, const int* __restrict__ dst,
                               int E, int* __restrict__ nxt, int* __restrict__ csr) {
    int i = blockIdx.x * blockDim.x + threadIdx.x;
    if (i < E) {
        int p = atomicAdd(&nxt[dst[i]], 1);
        csr[p] = src[i];
    }
}

// ---------------- layer 1 GEMM: h1 = x @ W1 (128->64), alphas ----------------

__global__ __launch_bounds__(256)
void gemm1_kernel(const float* __restrict__ x, const float* __restrict__ W1,
                  const float* __restrict__ a_s, const float* __restrict__ a_d,
                  float* __restrict__ h, float* __restrict__ as_o, float* __restrict__ ad_o,
                  int N) {
    const int g = blockIdx.x * blockDim.x + threadIdx.x;
    const int row = min(g, N - 1);
    const float* __restrict__ xp = x + (size_t)row * 128;
    float z[64];
    #pragma unroll
    for (int j = 0; j < 64; ++j) z[j] = 0.f;
    #pragma unroll 2
    for (int c = 0; c < 32; ++c) {
        const float4 xv = *(const float4*)(xp + c * 4);
        const float* __restrict__ Wp = W1 + c * 4 * 64;
        #pragma unroll
        for (int j = 0; j < 64; ++j) z[j] = fmaf(xv.x, Wp[j], z[j]);
        #pragma unroll
        for (int j = 0; j < 64; ++j) z[j] = fmaf(xv.y, Wp[64 + j], z[j]);
        #pragma unroll
        for (int j = 0; j < 64; ++j) z[j] = fmaf(xv.z, Wp[128 + j], z[j]);
        #pragma unroll
        for (int j = 0; j < 64; ++j) z[j] = fmaf(xv.w, Wp[192 + j], z[j]);
    }
    float ps = 0.f, pd = 0.f;
    #pragma unroll
    for (int j = 0; j < 64; ++j) {
        ps = fmaf(z[j], a_s[j], ps);
        pd = fmaf(z[j], a_d[j], pd);
    }
    float* __restrict__ hp = h + (size_t)row * 64;
    #pragma unroll
    for (int j = 0; j < 16; ++j)
        *(float4*)(hp + j * 4) = make_float4(z[4*j], z[4*j+1], z[4*j+2], z[4*j+3]);
    as_o[row] = ps;
    ad_o[row] = pd;
}

// ---------------- per-dst aggregation, D=64 ----------------
// One wave per node; 8 gathers in flight.

__global__ __launch_bounds__(256)
void agg1_kernel(const int* __restrict__ R, const int* __restrict__ csr,
                 const float* __restrict__ as1, const float* __restrict__ ad1,
                 const float* __restrict__ h1, const float* __restrict__ b1,
                 float* __restrict__ h1a, int N) {
    const int lane = threadIdx.x & 63;
    const int node = (int)((blockIdx.x * blockDim.x + threadIdx.x) >> 6);
    if (node >= N) return;
    const int start = R[node], end = R[node + 1];
    const float ad = ad1[node];
    int s0 = 0; float w0 = 0.f;
    const int e0 = start + lane;
    if (e0 < end) { s0 = csr[e0]; w0 = __expf(lrelu(as1[s0] + ad)); }
    float dsum = w0;
    for (int base = start + 64; base < end; base += 64) {  // rare (deg>64)
        int e = base + lane;
        if (e < end) dsum += __expf(lrelu(as1[csr[e]] + ad));
    }
    dsum = wave_reduce_sum(dsum);
    const float inv = 1.f / (dsum + 1e-16f);
    const float* __restrict__ hb = h1 + lane;
    float acc = 0.f;
    const int cnt = min(64, end - start);
    int t = 0;
    for (; t + 8 <= cnt; t += 8) {
        int   st[8]; float wt[8];
        #pragma unroll
        for (int u = 0; u < 8; ++u) { st[u] = __shfl(s0, t + u, 64); }
        #pragma unroll
        for (int u = 0; u < 8; ++u) { wt[u] = __shfl(w0, t + u, 64); }
        float hv[8];
        #pragma unroll
        for (int u = 0; u < 8; ++u) hv[u] = hb[(size_t)st[u] * 64];
        #pragma unroll
        for (int u = 0; u < 8; ++u) acc = fmaf(wt[u], hv[u], acc);
    }
    for (; t < cnt; ++t) {
        int st = __shfl(s0, t, 64);
        float wt = __shfl(w0, t, 64);
        acc = fmaf(wt, hb[(size_t)st * 64], acc);
    }
    for (int base = start + 64; base < end; base += 64) {  // rare tail
        int e = base + lane;
        int s = 0; float w = 0.f;
        if (e < end) { s = csr[e]; w = __expf(lrelu(as1[s] + ad)); }
        int c2 = min(64, end - base);
        for (int u = 0; u < c2; ++u)
            acc = fmaf(__shfl(w, u, 64), hb[(size_t)__shfl(s, u, 64) * 64], acc);
    }
    acc = acc * inv + b1[lane];
    h1a[(size_t)node * 64 + lane] = fmaxf(acc, 0.f);
}

// ---------------- layer 2 GEMM: h2 = h1a @ W2 (64->128), alphas ----------------

__global__ __launch_bounds__(256)
void gemm2_kernel(const float* __restrict__ h1a, const float* __restrict__ W2,
                  const float* __restrict__ a_s, const float* __restrict__ a_d,
                  float* __restrict__ h2, float* __restrict__ as_o, float* __restrict__ ad_o,
                  int N) {
    const int g = blockIdx.x * blockDim.x + threadIdx.x;
    const int row = min(g, N - 1);
    const float* __restrict__ xp = h1a + (size_t)row * 64;
    float* __restrict__ hp = h2 + (size_t)row * 128;
    float ps = 0.f, pd = 0.f;
    for (int half = 0; half < 2; ++half) {
        float z[64];
        #pragma unroll
        for (int j = 0; j < 64; ++j) z[j] = 0.f;
        #pragma unroll 2
        for (int c = 0; c < 16; ++c) {
            const float4 xv = *(const float4*)(xp + c * 4);
            const float* __restrict__ Wp = W2 + (c * 4) * 128 + half * 64;
            #pragma unroll
            for (int j = 0; j < 64; ++j) z[j] = fmaf(xv.x, Wp[j], z[j]);
            #pragma unroll
            for (int j = 0; j < 64; ++j) z[j] = fmaf(xv.y, Wp[128 + j], z[j]);
            #pragma unroll
            for (int j = 0; j < 64; ++j) z[j] = fmaf(xv.z, Wp[256 + j], z[j]);
            #pragma unroll
            for (int j = 0; j < 64; ++j) z[j] = fmaf(xv.w, Wp[384 + j], z[j]);
        }
        const float* __restrict__ asp = a_s + half * 64;
        const float* __restrict__ adp = a_d + half * 64;
        #pragma unroll
        for (int j = 0; j < 64; ++j) {
            ps = fmaf(z[j], asp[j], ps);
            pd = fmaf(z[j], adp[j], pd);
        }
        float* __restrict__ op = hp + half * 64;
        #pragma unroll
        for (int j = 0; j < 16; ++j)
            *(float4*)(op + j * 4) = make_float4(z[4*j], z[4*j+1], z[4*j+2], z[4*j+3]);
    }
    as_o[row] = ps;
    ad_o[row] = pd;
}

// ---------------- per-dst aggregation, D=128 ----------------
// Column-pair float2 layout; 8 gathers in flight.

__global__ __launch_bounds__(256)
void agg2_kernel(const int* __restrict__ R, const int* __restrict__ csr,
                 const float* __restrict__ as2, const float* __restrict__ ad2,
                 const float* __restrict__ h2, const float* __restrict__ b2,
                 float* __restrict__ h2a, int N) {
    const int lane = threadIdx.x & 63;
    const int node = (int)((blockIdx.x * blockDim.x + threadIdx.x) >> 6);
    if (node >= N) return;
    const int start = R[node], end = R[node + 1];
    const float ad = ad2[node];
    int s0 = 0; float w0 = 0.f;
    const int e0 = start + lane;
    if (e0 < end) { s0 = csr[e0]; w0 = __expf(lrelu(as2[s0] + ad)); }
    float dsum = w0;
    for (int base = start + 64; base < end; base += 64) {   // rare (deg>64)
        int e = base + lane;
        if (e < end) dsum += __expf(lrelu(as2[csr[e]] + ad));
    }
    dsum = wave_reduce_sum(dsum);
    const float inv = 1.f / (dsum + 1e-16f);
    const float* __restrict__ hb = h2 + 2 * lane;
    float a0 = 0.f, a1 = 0.f;
    const int cnt = min(64, end - start);
    int t = 0;
    for (; t + 8 <= cnt; t += 8) {
        int   st[8]; float wt[8];
        #pragma unroll
        for (int u = 0; u < 8; ++u) { st[u] = __shfl(s0, t + u, 64); }
        #pragma unroll
        for (int u = 0; u < 8; ++u) { wt[u] = __shfl(w0, t + u, 64); }
        float2 hv[8];
        #pragma unroll
        for (int u = 0; u < 8; ++u) hv[u] = *(const float2*)(hb + (size_t)st[u] * 128);
        #pragma unroll
        for (int u = 0; u < 8; ++u) {
            a0 = fmaf(wt[u], hv[u].x, a0);
            a1 = fmaf(wt[u], hv[u].y, a1);
        }
    }
    for (; t < cnt; ++t) {
        int st = __shfl(s0, t, 64);
        float wt = __shfl(w0, t, 64);
        const float2 hv = *(const float2*)(hb + (size_t)st * 128);
        a0 = fmaf(wt, hv.x, a0);
        a1 = fmaf(wt, hv.y, a1);
    }
    for (int base = start + 64; base < end; base += 64) {   // rare tail
        int e = base + lane;
        int s = 0; float w = 0.f;
        if (e < end) { s = csr[e]; w = __expf(lrelu(as2[s] + ad)); }
        int c2 = min(64, end - base);
        for (int u = 0; u < c2; ++u) {
            int st = __shfl(s, u, 64);
            float wt = __shfl(w, u, 64);
            const float2 hv = *(const float2*)(hb + (size_t)st * 128);
            a0 = fmaf(wt, hv.x, a0);
            a1 = fmaf(wt, hv.y, a1);
        }
    }
    const float2 bv = *(const float2*)(b2 + 2 * lane);
    *(float2*)(h2a + (size_t)node * 128 + 2 * lane) =
        make_float2(fmaxf(a0 * inv + bv.x, 0.f), fmaxf(a1 * inv + bv.y, 0.f));
}

// ---------------- fused MLP head: thread-per-row, LDS z-row ----------------
// Block = 192 threads; per-thread 65-float padded LDS row (49.9KB static).
// No barriers needed: each thread reads/writes only its own LDS row.
// (Measured variant from the 741.9us run; bounded codegen.)

__global__ __launch_bounds__(192)
void mlp_kernel(const float* __restrict__ h2a,
                const float* __restrict__ l1w, const float* __restrict__ l1b,
                const float* __restrict__ l2w, const float* __restrict__ l2b,
                const float* __restrict__ l11w, const float* __restrict__ l11b,
                const float* __restrict__ lVw,
                float* __restrict__ out, float* __restrict__ partials, int N) {
    __shared__ float zs[192 * 65];
    __shared__ float vsh[3];
    const int tid = threadIdx.x;
    const int g = blockIdx.x * 192 + tid;
    const int row = min(g, N - 1);
    float* __restrict__ zrow = &zs[tid * 65];

    // layer 1: z1 = h2a_row @ l1w + l1b   (128 -> 64)
    const float* __restrict__ xp = h2a + (size_t)row * 128;
    float z1[64];
    #pragma unroll
    for (int j = 0; j < 64; ++j) z1[j] = l1b[j];
    #pragma unroll 2
    for (int c = 0; c < 32; ++c) {
        const float4 xv = *(const float4*)(xp + c * 4);
        const float* __restrict__ Wp = l1w + c * 4 * 64;
        #pragma unroll
        for (int j = 0; j < 64; ++j) z1[j] = fmaf(xv.x, Wp[j], z1[j]);
        #pragma unroll
        for (int j = 0; j < 64; ++j) z1[j] = fmaf(xv.y, Wp[64 + j], z1[j]);
        #pragma unroll
        for (int j = 0; j < 64; ++j) z1[j] = fmaf(xv.z, Wp[128 + j], z1[j]);
        #pragma unroll
        for (int j = 0; j < 64; ++j) z1[j] = fmaf(xv.w, Wp[192 + j], z1[j]);
    }
    #pragma unroll
    for (int j = 0; j < 64; ++j) zrow[j] = z1[j];

    // layer 2: z2 = z1 @ l2w + l2b   (64 -> 64)
    float z2[64];
    #pragma unroll
    for (int j = 0; j < 64; ++j) z2[j] = l2b[j];
    #pragma unroll 4
    for (int k = 0; k < 64; ++k) {
        const float zk = zrow[k];
        const float* __restrict__ Wp = l2w + k * 64;
        #pragma unroll
        for (int j = 0; j < 64; ++j) z2[j] = fmaf(zk, Wp[j], z2[j]);
    }

    // value partial: <z2, lVw>, zeroed for duplicate tail threads
    float v = 0.f;
    #pragma unroll
    for (int j = 0; j < 64; ++j) v = fmaf(z2[j], lVw[j], v);
    if (g >= N) v = 0.f;

    #pragma unroll
    for (int j = 0; j < 64; ++j) zrow[j] = z2[j];

    // layer 3: out = tanh(z2 @ l11w + l11b)   (64 -> 64)
    float z3[64];
    #pragma unroll
    for (int j = 0; j < 64; ++j) z3[j] = l11b[j];
    #pragma unroll 4
    for (int k = 0; k < 64; ++k) {
        const float zk = zrow[k];
        const float* __restrict__ Wp = l11w + k * 64;
        #pragma unroll
        for (int j = 0; j < 64; ++j) z3[j] = fmaf(zk, Wp[j], z3[j]);
    }
    float* __restrict__ op = out + (size_t)row * 64;
    #pragma unroll
    for (int j = 0; j < 16; ++j)
        *(float4*)(op + j * 4) = make_float4(fast_tanh(z3[4*j]),   fast_tanh(z3[4*j+1]),
                                             fast_tanh(z3[4*j+2]), fast_tanh(z3[4*j+3]));

    // block partial for the value mean
    v = wave_reduce_sum(v);
    const int lane = tid & 63, wid = tid >> 6;
    if (lane == 0) vsh[wid] = v;
    __syncthreads();
    if (tid == 0) partials[blockIdx.x] = vsh[0] + vsh[1] + vsh[2];
}

__global__ void reduce_kernel(const float* __restrict__ partials, int n,
                              float* __restrict__ out_val,
                              const float* __restrict__ lVb, float invN) {
    __shared__ float sh[16];
    float s = 0.f;
    for (int i = threadIdx.x; i < n; i += 1024) s += partials[i];
    s = wave_reduce_sum(s);
    const int lane = threadIdx.x & 63, wid = threadIdx.x >> 6;
    if (lane == 0) sh[wid] = s;
    __syncthreads();
    if (wid == 0) {
        float t = (lane < 16) ? sh[lane] : 0.f;
        t = wave_reduce_sum(t);
        if (lane == 0) *out_val = t * invN + lVb[0];
    }
}

// ---------------- launch ----------------

extern "C" void kernel_launch(void* const* d_in, const int* in_sizes, int n_in,
                              void* d_out, int out_size, void* d_ws, size_t ws_size,
                              hipStream_t stream) {
    const float* x    = (const float*)d_in[0];
    const int*   ei   = (const int*)d_in[1];
    const float* W1   = (const float*)d_in[2];
    const float* a_s1 = (const float*)d_in[3];
    const float* a_d1 = (const float*)d_in[4];
    const float* b1   = (const float*)d_in[5];
    const float* W2   = (const float*)d_in[6];
    const float* a_s2 = (const float*)d_in[7];
    const float* a_d2 = (const float*)d_in[8];
    const float* b2   = (const float*)d_in[9];
    const float* l1w  = (const float*)d_in[10];
    const float* l1b  = (const float*)d_in[11];
    const float* l2w  = (const float*)d_in[12];
    const float* l2b  = (const float*)d_in[13];
    const float* l11w = (const float*)d_in[14];
    const float* l11b = (const float*)d_in[15];
    const float* lVw  = (const float*)d_in[16];
    const float* lVb  = (const float*)d_in[17];
    float* out = (float*)d_out;

    const int N = in_sizes[0] / 128;
    const int E = in_sizes[1] / 2;
    const int* src = ei;
    const int* dst = ei + E;

    char* base = (char*)d_ws;
    size_t off = 0;
    auto alloc = [&](size_t bytes) -> char* {
        char* p = base + off;
        off = (off + bytes + 255) & ~(size_t)255;
        return p;
    };
    float* h1   = (float*)alloc((size_t)N * 64 * 4);   // region A lower half
    float* h1a  = (float*)alloc((size_t)N * 64 * 4);   // region A upper half
    float* h2a  = h1;                                   // alias: h1|h1a dead by agg2
    float* h2   = (float*)alloc((size_t)N * 128 * 4);
    float* as1  = (float*)alloc((size_t)N * 4);
    float* ad1  = (float*)alloc((size_t)N * 4);
    float* as2  = (float*)alloc((size_t)N * 4);
    float* ad2  = (float*)alloc((size_t)N * 4);
    int*   C    = (int*)alloc((size_t)N * 4);
    int*   R    = (int*)alloc((size_t)(N + 1) * 4);
    int*   nxt  = (int*)alloc((size_t)N * 4);
    int*   csr  = (int*)alloc((size_t)E * 4);
    int*   bsum = (int*)alloc((size_t)128 * 4);
    const int nB256 = (N + 255) / 256;                 // gemm blocks
    const int nBmlp = (N + 191) / 192;                 // mlp blocks (192 rows)
    const int nWB   = (N * 64 + 255) / 256;            // agg blocks (1 wave/node)
    float* partials = (float*)alloc((size_t)nBmlp * 4);
    (void)ws_size; (void)n_in; (void)out_size;

    hipMemsetAsync(C, 0, (size_t)N * 4, stream);
    const int egrid = (E + 255) / 256;
    const int nbs = (N + 1023) / 1024;
    hist_kernel<<<egrid, 256, 0, stream>>>(dst, E, C);
    scan_local_kernel<<<nbs, 1024, 0, stream>>>(C, R, bsum, N);
    scan_bsum_kernel<<<1, 64, 0, stream>>>(bsum, nbs);
    scan_apply_kernel<<<nbs, 1024, 0, stream>>>(R, nxt, bsum, N, E);
    scatter_kernel<<<egrid, 256, 0, stream>>>(src, dst, E, nxt, csr);
    gemm1_kernel<<<nB256, 256, 0, stream>>>(x, W1, a_s1, a_d1, h1, as1, ad1, N);
    agg1_kernel<<<nWB, 256, 0, stream>>>(R, csr, as1, ad1, h1, b1, h1a, N);
    gemm2_kernel<<<nB256, 256, 0, stream>>>(h1a, W2, a_s2, a_d2, h2, as2, ad2, N);
    agg2_kernel<<<nWB, 256, 0, stream>>>(R, csr, as2, ad2, h2, b2, h2a, N);
    mlp_kernel<<<nBmlp, 192, 0, stream>>>(h2a, l1w, l1b, l2w, l2b, l11w, l11b, lVw,
                                          out, partials, N);
    reduce_kernel<<<1, 1024, 0, stream>>>(partials, nBmlp, out + (size_t)N * 64, lVb,
                                          1.0f / (float)N);
}